// Round 4
// baseline (559.190 us; speedup 1.0000x reference)
//
#include <hip/hip_runtime.h>

// Problem constants
#define NB 10000          // batch
#define NC 64             // channels
#define NE 10             // elements
#define DIN 40            // 1+3+9+27
#define NM 13             // 1+3+9 output m's
#define NPAIR 820         // 40*41/2 symmetric pairs
#define XS 41             // LDS row stride for x (odd mod 32 -> conflict-free)

// ---------------------------------------------------------------------------
// Kernel 1: pack symmetric U2 coefficients into [pair][16] layout (x2 off-diag)
// and U1 into [i][16]. Runs every launch (d_ws is re-poisoned by the harness).
// u1Pack MUST immediately follow coefPack: the main kernel's rolling prefetch
// reads up to pair slot 821 (overrun lands in u1Pack, values unused).
// ---------------------------------------------------------------------------
__global__ void psc_pack_kernel(const float* __restrict__ U2_0,
                                const float* __restrict__ U2_1,
                                const float* __restrict__ U2_2,
                                const float* __restrict__ U1_0,
                                const float* __restrict__ U1_1,
                                const float* __restrict__ U1_2,
                                float* __restrict__ coefPack,   // [820][16]
                                float* __restrict__ u1Pack)     // [40][16]
{
    int tid = blockIdx.x * blockDim.x + threadIdx.x;
    if (tid < 1600 * 16) {
        int m = tid & 15;
        int idx = tid >> 4;
        int i = idx / 40, j = idx % 40;
        if (j < i) return;                       // only i<=j pairs exist
        int p = i * 40 - ((i * (i - 1)) >> 1) + (j - i);
        float s = (i == j) ? 1.0f : 2.0f;        // symmetric fold
        float v = 0.0f;
        if (m == 0)       v = U2_0[i * 40 + j];
        else if (m < 4)   v = U2_1[(m - 1) * 1600 + i * 40 + j];
        else if (m < 13)  v = U2_2[(m - 4) * 1600 + i * 40 + j];
        coefPack[p * 16 + m] = v * s;            // m=13..15 poison, never used
    } else if (tid < 1600 * 16 + 40 * 16) {
        int t = tid - 1600 * 16;
        int m = t & 15;
        int i = t >> 4;
        float v = 0.0f;
        if (m == 0)       v = U1_0[i];
        else if (m < 4)   v = U1_1[(m - 1) * 40 + i];
        else if (m < 13)  v = U1_2[(m - 4) * 40 + i];
        u1Pack[i * 16 + m] = v;
    }
}

#define FMA13(Q0, Q1, Q2, Q3, XX)                                     \
    acc2[0]  += (Q0).x * (XX);  acc2[1]  += (Q0).y * (XX);            \
    acc2[2]  += (Q0).z * (XX);  acc2[3]  += (Q0).w * (XX);            \
    acc2[4]  += (Q1).x * (XX);  acc2[5]  += (Q1).y * (XX);            \
    acc2[6]  += (Q1).z * (XX);  acc2[7]  += (Q1).w * (XX);            \
    acc2[8]  += (Q2).x * (XX);  acc2[9]  += (Q2).y * (XX);            \
    acc2[10] += (Q2).z * (XX);  acc2[11] += (Q2).w * (XX);            \
    acc2[12] += (Q3).x * (XX);

// advance wave-uniform prefetch position (ip,jp) through the i<=j triangle;
// clamps harmlessly in the overrun region past pair 819.
#define ADV()                                                         \
    do {                                                              \
        ++jp;                                                         \
        if (jp >= DIN) {                                              \
            if (ip < DIN - 1) ++ip;                                   \
            jp = ip;                                                  \
            xip = xrow[ip];                                           \
        }                                                             \
    } while (0)

// ---------------------------------------------------------------------------
// Kernel 2: main fused product-basis + channel-mix + skip-connection.
// One wave (64 threads) per b; thread = channel c. 10.5 KB LDS -> 15 waves/CU.
// ---------------------------------------------------------------------------
__global__ __launch_bounds__(64, 4)
void psc_main_kernel(const float* __restrict__ f0, const float* __restrict__ f1,
                     const float* __restrict__ f2, const float* __restrict__ f3,
                     const float* __restrict__ attrs,
                     const float* __restrict__ W1_0, const float* __restrict__ W2_0,
                     const float* __restrict__ Wlin_0, const float* __restrict__ sc_0,
                     const float* __restrict__ W1_1, const float* __restrict__ W2_1,
                     const float* __restrict__ Wlin_1, const float* __restrict__ sc_1,
                     const float* __restrict__ W1_2, const float* __restrict__ W2_2,
                     const float* __restrict__ Wlin_2, const float* __restrict__ sc_2,
                     const float* __restrict__ coefPack,
                     const float* __restrict__ u1Pack,
                     float* __restrict__ out)
{
    __shared__ float xs[64 * XS];     // 10496 B; rows are thread-private after load

    const int c = threadIdx.x;
    const int b = blockIdx.x;

    // ---- cooperative, coalesced load of this b's feats into LDS ----
    xs[c * XS + 0] = f0[b * 64 + c];
    #pragma unroll
    for (int t = 0; t < 3; ++t) {
        int idx = c + 64 * t;                 // 192 = 3*64
        int cc = idx / 3, k = idx % 3;
        xs[cc * XS + 1 + k] = f1[b * 192 + idx];
    }
    #pragma unroll
    for (int t = 0; t < 9; ++t) {
        int idx = c + 64 * t;                 // 576
        int cc = idx / 9, k = idx % 9;
        xs[cc * XS + 4 + k] = f2[b * 576 + idx];
    }
    #pragma unroll
    for (int t = 0; t < 27; ++t) {
        int idx = c + 64 * t;                 // 1728
        int cc = idx / 27, k = idx % 27;
        xs[cc * XS + 13 + k] = f3[b * 1728 + idx];
    }
    __syncthreads();

    // ---- element-aware channel weights: w = attrs[b] . W[:,c] ----
    float w1l0 = 0.f, w2l0 = 0.f, w1l1 = 0.f, w2l1 = 0.f, w1l2 = 0.f, w2l2 = 0.f;
    #pragma unroll
    for (int e = 0; e < NE; ++e) {
        float a = attrs[b * NE + e];          // wave-uniform -> scalar load
        w1l0 += a * W1_0[e * 64 + c];
        w2l0 += a * W2_0[e * 64 + c];
        w1l1 += a * W1_1[e * 64 + c];
        w2l1 += a * W2_1[e * 64 + c];
        w1l2 += a * W1_2[e * 64 + c];
        w2l2 += a * W2_2[e * 64 + c];
    }

    const float* xrow = &xs[c * XS];

    // ---- a1: u1 contraction (40 x 13) ----
    float acc1[NM];
    #pragma unroll
    for (int m = 0; m < NM; ++m) acc1[m] = 0.f;
    #pragma unroll 4
    for (int i = 0; i < DIN; ++i) {
        float xi = xrow[i];
        const float4* u4 = (const float4*)&u1Pack[i * 16];
        float4 u0 = u4[0], u1v = u4[1], u2v = u4[2], u3v = u4[3];
        acc1[0]  += u0.x  * xi;  acc1[1]  += u0.y  * xi;
        acc1[2]  += u0.z  * xi;  acc1[3]  += u0.w  * xi;
        acc1[4]  += u1v.x * xi;  acc1[5]  += u1v.y * xi;
        acc1[6]  += u1v.z * xi;  acc1[7]  += u1v.w * xi;
        acc1[8]  += u2v.x * xi;  acc1[9]  += u2v.y * xi;
        acc1[10] += u2v.z * xi;  acc1[11] += u2v.w * xi;
        acc1[12] += u3v.x * xi;
    }

    // ---- a2: symmetric-pair contraction, 3-deep rotating prefetch ----
    // Pair p <-> (i,j), i<=j, i-major; pair p occupies coefPack[16p..16p+15].
    // Phases A/B/C hold pre-loaded coefs + x values; loads for pair p+3 issue
    // ~84 VALU cycles (per wave) before use -> ~330 wall-clock cycles at 4
    // resident waves/SIMD, covering L2 latency. 820 = 3*273 + 1: loop handles
    // pairs 0..818, epilogue pair 819. Overrun refills read pair slots 820/821
    // (= u1Pack[0..31]) and xrow[39] -- in-bounds, unused.
    float acc2[NM];
    #pragma unroll
    for (int m = 0; m < NM; ++m) acc2[m] = 0.f;

    {
        const float4* cp4 = (const float4*)coefPack;
        int ip = 0, jp = 0;                   // prefetch position, wave-uniform
        float xip = xrow[0];

        // prologue: phases A,B,C = pairs 0,1,2
        float4 A0 = cp4[0], A1 = cp4[1], A2 = cp4[2], A3 = cp4[3];
        float  xiA = xip, xjA = xrow[jp];
        ADV();
        float4 B0 = cp4[4], B1 = cp4[5], B2 = cp4[6], B3 = cp4[7];
        float  xiB = xip, xjB = xrow[jp];
        ADV();
        float4 C0 = cp4[8], C1 = cp4[9], C2 = cp4[10], C3 = cp4[11];
        float  xiC = xip, xjC = xrow[jp];
        ADV();
        cp4 += 12;                            // now at pair 3

        for (int k = 0; k < NPAIR / 3; ++k) { // 273 iters, pairs 0..818
            float xx = xiA * xjA;
            FMA13(A0, A1, A2, A3, xx);
            A0 = cp4[0]; A1 = cp4[1]; A2 = cp4[2]; A3 = cp4[3];
            xiA = xip; xjA = xrow[jp];
            ADV();

            xx = xiB * xjB;
            FMA13(B0, B1, B2, B3, xx);
            B0 = cp4[4]; B1 = cp4[5]; B2 = cp4[6]; B3 = cp4[7];
            xiB = xip; xjB = xrow[jp];
            ADV();

            xx = xiC * xjC;
            FMA13(C0, C1, C2, C3, xx);
            C0 = cp4[8]; C1 = cp4[9]; C2 = cp4[10]; C3 = cp4[11];
            xiC = xip; xjC = xrow[jp];
            ADV();

            cp4 += 12;
        }
        // epilogue: phase A holds pair 819 (B=820, C=821 are overrun garbage)
        float xx = xiA * xjA;
        FMA13(A0, A1, A2, A3, xx);
    }

    // ---- basis = a1*w1 + a2*w2; transpose into dead x-region of LDS ----
    float basisv[NM];
    basisv[0] = acc1[0] * w1l0 + acc2[0] * w2l0;
    #pragma unroll
    for (int m = 1; m < 4; ++m)  basisv[m] = acc1[m] * w1l1 + acc2[m] * w2l1;
    #pragma unroll
    for (int m = 4; m < NM; ++m) basisv[m] = acc1[m] * w1l2 + acc2[m] * w2l2;

    __syncthreads();                          // all lanes done reading xs
    #pragma unroll
    for (int m = 0; m < NM; ++m)
        xs[m * 64 + c] = basisv[m];           // basisT[m][c]; 2 lanes/bank = free
    __syncthreads();

    // ---- channel mix: out[b,o,m] = sum_cc basisT[m][cc] * Wlin_l[cc,o] ----
    // basisT rows are 16B-aligned -> uniform float4 broadcast reads.
    const int o = c;
    float om[NM];
    #pragma unroll
    for (int m = 0; m < NM; ++m) om[m] = 0.f;

    for (int c4 = 0; c4 < 16; ++c4) {
        const int cc = c4 * 4;
        float p0 = Wlin_0[(cc + 0) * 64 + o], p1 = Wlin_0[(cc + 1) * 64 + o],
              p2 = Wlin_0[(cc + 2) * 64 + o], p3 = Wlin_0[(cc + 3) * 64 + o];
        float q0 = Wlin_1[(cc + 0) * 64 + o], q1 = Wlin_1[(cc + 1) * 64 + o],
              q2 = Wlin_1[(cc + 2) * 64 + o], q3 = Wlin_1[(cc + 3) * 64 + o];
        float r0 = Wlin_2[(cc + 0) * 64 + o], r1 = Wlin_2[(cc + 1) * 64 + o],
              r2 = Wlin_2[(cc + 2) * 64 + o], r3 = Wlin_2[(cc + 3) * 64 + o];

        float4 t;
        t = *(const float4*)&xs[0 * 64 + cc];
        om[0] += t.x * p0 + t.y * p1 + t.z * p2 + t.w * p3;
        #pragma unroll
        for (int m = 1; m < 4; ++m) {
            t = *(const float4*)&xs[m * 64 + cc];
            om[m] += t.x * q0 + t.y * q1 + t.z * q2 + t.w * q3;
        }
        #pragma unroll
        for (int m = 4; m < NM; ++m) {
            t = *(const float4*)&xs[m * 64 + cc];
            om[m] += t.x * r0 + t.y * r1 + t.z * r2 + t.w * r3;
        }
    }

    // ---- add skip connection, write outputs (tuple concat layout) ----
    const int bo = b * 64 + o;
    out[bo] = om[0] + sc_0[bo];
    #pragma unroll
    for (int k = 0; k < 3; ++k)
        out[NB * 64 + bo * 3 + k] = om[1 + k] + sc_1[bo * 3 + k];
    #pragma unroll
    for (int k = 0; k < 9; ++k)
        out[NB * 64 * 4 + bo * 9 + k] = om[4 + k] + sc_2[bo * 9 + k];
}

// ---------------------------------------------------------------------------
extern "C" void kernel_launch(void* const* d_in, const int* in_sizes, int n_in,
                              void* d_out, int out_size, void* d_ws, size_t ws_size,
                              hipStream_t stream) {
    const float* f0    = (const float*)d_in[0];
    const float* f1    = (const float*)d_in[1];
    const float* f2    = (const float*)d_in[2];
    const float* f3    = (const float*)d_in[3];
    const float* attrs = (const float*)d_in[4];
    const float* U2_0  = (const float*)d_in[5];
    const float* U1_0  = (const float*)d_in[6];
    const float* W1_0  = (const float*)d_in[7];
    const float* W2_0  = (const float*)d_in[8];
    const float* Wl_0  = (const float*)d_in[9];
    const float* sc_0  = (const float*)d_in[10];
    const float* U2_1  = (const float*)d_in[11];
    const float* U1_1  = (const float*)d_in[12];
    const float* W1_1  = (const float*)d_in[13];
    const float* W2_1  = (const float*)d_in[14];
    const float* Wl_1  = (const float*)d_in[15];
    const float* sc_1  = (const float*)d_in[16];
    const float* U2_2  = (const float*)d_in[17];
    const float* U1_2  = (const float*)d_in[18];
    const float* W1_2  = (const float*)d_in[19];
    const float* W2_2  = (const float*)d_in[20];
    const float* Wl_2  = (const float*)d_in[21];
    const float* sc_2  = (const float*)d_in[22];

    float* coefPack = (float*)d_ws;               // 820*16 floats
    float* u1Pack   = coefPack + NPAIR * 16;      // 40*16 floats (must follow!)
    float* out      = (float*)d_out;

    int packThreads = 1600 * 16 + 40 * 16;
    psc_pack_kernel<<<(packThreads + 255) / 256, 256, 0, stream>>>(
        U2_0, U2_1, U2_2, U1_0, U1_1, U1_2, coefPack, u1Pack);

    psc_main_kernel<<<NB, 64, 0, stream>>>(
        f0, f1, f2, f3, attrs,
        W1_0, W2_0, Wl_0, sc_0,
        W1_1, W2_1, Wl_1, sc_1,
        W1_2, W2_2, Wl_2, sc_2,
        coefPack, u1Pack, out);
}